// Round 15
// baseline (667.401 us; speedup 1.0000x reference)
//
#include <hip/hip_runtime.h>
#include <hip/hip_bf16.h>

// GNODE fully fused: y' = relu(y@W1+b1)@W2+b2, RK4(3/8) x10 steps (h=0.1),
// out = y@Wl+bl.  N=200000 rows, 128 ch, 64 out ch.
//
// Round 15 = r14 (split-channel wave pair, AGPR weights, 477us) + DUAL
// ROW-TILE per wave.  r14's limiter: the 2 resident waves are barrier-locked
// into the same phase -> VALU phase and MFMA phase serialize (wall 2815cy =
// 1365 VALU + 1030 MFMA + stalls).  Fix: each wave now runs TWO independent
// 16-row tiles (A,B) of its channel half; tile B's frag-build VALU issues
// under tile A's in-flight MFMAs (separate pipes, m114) and per-barrier work
// doubles.  Register audit vs r10's spill: weights AGPR-resident (128, not
// staged), channel-split halves state -> arch ~150 (yA/yB 32 + U 32 + V 32
// + frags 32 + misc), AGPR ~160 (weights 128 + acc 32).  1 wave/SIMD.
//
// State recurrences (template<MODE>):
//   M1: U<-k1   M2: V<-k2   M3: U<-U+3(V+k3), V<-U-V+k3   M4: y+=h/8(U+k4)
// Layout identity (mfma_f32_16x16x32_bf16, HW-verified m89):
//   D:      ch = 16*mb + 4*(lane>>4) + r,               batch = lane&15
//   B-frag: ch = 32*kb + 16*(j>>2) + 4*(lane>>4)+(j&3),  batch = lane&15
// => frag[kb][j] = state[kb*8+j]; wave wid owns global kb {2wid, 2wid+1}
//    i.e. state elems [16*wid, 16*wid+16) (local e' = e - 16*wid).
// Barrier safety: 2 barriers/feval on alternating buffers (arg, h) ->
// every buffer rewrite is separated from its previous reads by >=1 barrier.

typedef __attribute__((ext_vector_type(8))) short bf16x8;
typedef __attribute__((ext_vector_type(4))) float f32x4;

constexpr float HS = 0.1f;

__device__ __forceinline__ short bf16s(float f) {
    return __builtin_bit_cast(short, (__bf16)f);      // -> v_cvt_pk_bf16_f32 (paired)
}
__device__ __forceinline__ bf16x8 bc8(uint4 u) { return __builtin_bit_cast(bf16x8, u); }

#define MFMA_BF16 __builtin_amdgcn_mfma_f32_16x16x32_bf16

// B-frag for local kk (0/1) from a tile's 16 local state elems.
template<int M>
__device__ __forceinline__ bf16x8 build_frag(const float (&y)[16], const float (&U)[16],
                                             const float (&V)[16], int kk) {
    bf16x8 f;
    #pragma unroll
    for (int j = 0; j < 8; ++j) {
        const int e = kk * 8 + j;
        float a;
        if (M == 1)      a = y[e];
        else if (M == 2) a = fmaf(HS * (1.f / 3.f), U[e], y[e]);
        else if (M == 3) a = fmaf(-HS * (1.f / 3.f), U[e], fmaf(HS, V[e], y[e]));
        else             a = fmaf(HS, V[e], y[e]);
        f[j] = bf16s(a);
    }
    return f;
}

// Mode-fused writeback for one tile (local e' = 4*mb' + r).
template<int M>
__device__ __forceinline__ void writeback(const f32x4 (&a2)[4], float (&y)[16],
                                          float (&U)[16], float (&V)[16]) {
    #pragma unroll
    for (int mb = 0; mb < 4; ++mb)
        #pragma unroll
        for (int r = 0; r < 4; ++r) {
            const int e = mb * 4 + r;
            const float k = a2[mb][r];
            if (M == 1)      U[e] = k;
            else if (M == 2) V[e] = k;
            else if (M == 3) {
                const float u = U[e], v = V[e];
                U[e] = fmaf(3.f, v + k, u);
                V[e] = u - v + k;
            } else {
                y[e] = fmaf(HS * 0.125f, U[e] + k, y[e]);
            }
        }
}

// One f-eval for BOTH tiles of this wave's 64-out-ch half.
// Weight frags wid-relative: f = mb*4 + kv_loc, kv_loc 0/1 own kbs, 2/3 other's.
template<int M>
__device__ __forceinline__ void feval2(const bf16x8 (&w1r)[16], const bf16x8 (&w2r)[16],
                                       const float* __restrict__ sbf1,
                                       const float* __restrict__ sbf2,
                                       uint4* __restrict__ myA, const uint4* __restrict__ otA,
                                       uint4* __restrict__ myB, const uint4* __restrict__ otB,
                                       uint4* __restrict__ myHA, const uint4* __restrict__ otHA,
                                       uint4* __restrict__ myHB, const uint4* __restrict__ otHB,
                                       float (&yA)[16], float (&UA)[16], float (&VA)[16],
                                       float (&yB)[16], float (&UB)[16], float (&VB)[16])
{
    // ---- own arg frags (regs) -> LDS; bias init overlaps the barrier
    const bf16x8 a0A = build_frag<M>(yA, UA, VA, 0);
    const bf16x8 a1A = build_frag<M>(yA, UA, VA, 1);
    const bf16x8 a0B = build_frag<M>(yB, UB, VB, 0);
    const bf16x8 a1B = build_frag<M>(yB, UB, VB, 1);
    myA[0]  = __builtin_bit_cast(uint4, a0A);
    myA[64] = __builtin_bit_cast(uint4, a1A);
    myB[0]  = __builtin_bit_cast(uint4, a0B);
    myB[64] = __builtin_bit_cast(uint4, a1B);
    f32x4 accA[4], accB[4];
    #pragma unroll
    for (int mb = 0; mb < 4; ++mb) {
        const f32x4 b = *(const f32x4*)&sbf1[mb * 16];
        accA[mb] = b; accB[mb] = b;
    }
    __syncthreads();
    const bf16x8 a2A = bc8(otA[0]);
    const bf16x8 a3A = bc8(otA[64]);
    const bf16x8 a2B = bc8(otB[0]);
    const bf16x8 a3B = bc8(otB[64]);

    // ---- matmul1: 32 MFMA, A/B interleaved (independent acc chains)
    __builtin_amdgcn_s_setprio(1);
    #pragma unroll
    for (int mb = 0; mb < 4; ++mb) accA[mb] = MFMA_BF16(w1r[mb * 4 + 0], a0A, accA[mb], 0, 0, 0);
    #pragma unroll
    for (int mb = 0; mb < 4; ++mb) accB[mb] = MFMA_BF16(w1r[mb * 4 + 0], a0B, accB[mb], 0, 0, 0);
    #pragma unroll
    for (int mb = 0; mb < 4; ++mb) accA[mb] = MFMA_BF16(w1r[mb * 4 + 1], a1A, accA[mb], 0, 0, 0);
    #pragma unroll
    for (int mb = 0; mb < 4; ++mb) accB[mb] = MFMA_BF16(w1r[mb * 4 + 1], a1B, accB[mb], 0, 0, 0);
    #pragma unroll
    for (int mb = 0; mb < 4; ++mb) accA[mb] = MFMA_BF16(w1r[mb * 4 + 2], a2A, accA[mb], 0, 0, 0);
    #pragma unroll
    for (int mb = 0; mb < 4; ++mb) accB[mb] = MFMA_BF16(w1r[mb * 4 + 2], a2B, accB[mb], 0, 0, 0);
    #pragma unroll
    for (int mb = 0; mb < 4; ++mb) accA[mb] = MFMA_BF16(w1r[mb * 4 + 3], a3A, accA[mb], 0, 0, 0);
    #pragma unroll
    for (int mb = 0; mb < 4; ++mb) accB[mb] = MFMA_BF16(w1r[mb * 4 + 3], a3B, accB[mb], 0, 0, 0);
    __builtin_amdgcn_s_setprio(0);

    // ---- relu -> own h frags (adjacent pairs: packable cvt)
    bf16x8 hA0, hA1, hB0, hB1;
    #pragma unroll
    for (int j = 0; j < 8; ++j) {
        hA0[j] = bf16s(fmaxf(accA[(j >> 2)][j & 3], 0.f));
        hA1[j] = bf16s(fmaxf(accA[2 + (j >> 2)][j & 3], 0.f));
        hB0[j] = bf16s(fmaxf(accB[(j >> 2)][j & 3], 0.f));
        hB1[j] = bf16s(fmaxf(accB[2 + (j >> 2)][j & 3], 0.f));
    }
    myHA[0]  = __builtin_bit_cast(uint4, hA0);
    myHA[64] = __builtin_bit_cast(uint4, hA1);
    myHB[0]  = __builtin_bit_cast(uint4, hB0);
    myHB[64] = __builtin_bit_cast(uint4, hB1);
    f32x4 a2Av[4], a2Bv[4];
    #pragma unroll
    for (int mb = 0; mb < 4; ++mb) {
        const f32x4 b = *(const f32x4*)&sbf2[mb * 16];
        a2Av[mb] = b; a2Bv[mb] = b;
    }
    __syncthreads();
    const bf16x8 h2A = bc8(otHA[0]);
    const bf16x8 h3A = bc8(otHA[64]);
    const bf16x8 h2B = bc8(otHB[0]);
    const bf16x8 h3B = bc8(otHB[64]);

    // ---- matmul2: 32 MFMA
    __builtin_amdgcn_s_setprio(1);
    #pragma unroll
    for (int mb = 0; mb < 4; ++mb) a2Av[mb] = MFMA_BF16(w2r[mb * 4 + 0], hA0, a2Av[mb], 0, 0, 0);
    #pragma unroll
    for (int mb = 0; mb < 4; ++mb) a2Bv[mb] = MFMA_BF16(w2r[mb * 4 + 0], hB0, a2Bv[mb], 0, 0, 0);
    #pragma unroll
    for (int mb = 0; mb < 4; ++mb) a2Av[mb] = MFMA_BF16(w2r[mb * 4 + 1], hA1, a2Av[mb], 0, 0, 0);
    #pragma unroll
    for (int mb = 0; mb < 4; ++mb) a2Bv[mb] = MFMA_BF16(w2r[mb * 4 + 1], hB1, a2Bv[mb], 0, 0, 0);
    #pragma unroll
    for (int mb = 0; mb < 4; ++mb) a2Av[mb] = MFMA_BF16(w2r[mb * 4 + 2], h2A, a2Av[mb], 0, 0, 0);
    #pragma unroll
    for (int mb = 0; mb < 4; ++mb) a2Bv[mb] = MFMA_BF16(w2r[mb * 4 + 2], h2B, a2Bv[mb], 0, 0, 0);
    #pragma unroll
    for (int mb = 0; mb < 4; ++mb) a2Av[mb] = MFMA_BF16(w2r[mb * 4 + 3], h3A, a2Av[mb], 0, 0, 0);
    #pragma unroll
    for (int mb = 0; mb < 4; ++mb) a2Bv[mb] = MFMA_BF16(w2r[mb * 4 + 3], h3B, a2Bv[mb], 0, 0, 0);
    __builtin_amdgcn_s_setprio(0);

    // ---- writebacks
    writeback<M>(a2Av, yA, UA, VA);
    writeback<M>(a2Bv, yB, UB, VB);
}

__global__ __launch_bounds__(128) void gnode_kernel(
    const float* __restrict__ x, const uint4* __restrict__ wfr,
    const float* __restrict__ b1, const float* __restrict__ b2,
    const float* __restrict__ bl, float* __restrict__ out, int n)
{
    __shared__ uint4 argA[4][64], argB[4][64];   // 8KB arg exchange (tiles A,B)
    __shared__ uint4 hxA[4][64],  hxB[4][64];    // 8KB h exchange
    __shared__ float s_bf[256];                  // 1KB biases

    const int tid  = threadIdx.x;
    const int lane = tid & 63;
    const int wid  = tid >> 6;       // 0/1: which 64-out-ch half this wave owns
    const int g    = lane >> 4;
    const int c16  = lane & 15;
    const int rowA = blockIdx.x * 32 + c16;      // tile A row
    const int rowB = rowA + 16;                  // tile B row
    const int rcA  = rowA < n ? rowA : n - 1;
    const int rcB  = rowB < n ? rowB : n - 1;

    s_bf[tid]       = b1[tid];
    s_bf[128 + tid] = b2[tid];

    // ---- weights: this wave's halves, wid-RELATIVE kb order [own0,own1,oth0,oth1]
    bf16x8 w1r[16], w2r[16];
    #pragma unroll
    for (int f = 0; f < 16; ++f) {
        const int mb = f >> 2, kv = f & 3;
        const int kg = (kv < 2) ? (2 * wid + kv) : (2 * (1 - wid) + kv - 2);
        w1r[f] = bc8(wfr[((wid * 4 + mb) * 4 + kg) * 64 + lane]);
        w2r[f] = bc8(wfr[(32 + (wid * 4 + mb) * 4 + kg) * 64 + lane]);
    }

    // ---- hoisted LDS pointers
    uint4*       myA  = &argA[2 * wid][lane];
    const uint4* otA  = &argA[2 * (1 - wid)][lane];
    uint4*       myB  = &argB[2 * wid][lane];
    const uint4* otB  = &argB[2 * (1 - wid)][lane];
    uint4*       myHA = &hxA[2 * wid][lane];
    const uint4* otHA = &hxA[2 * (1 - wid)][lane];
    uint4*       myHB = &hxB[2 * wid][lane];
    const uint4* otHB = &hxB[2 * (1 - wid)][lane];
    const float* sbf1 = &s_bf[wid * 64 + g * 4];
    const float* sbf2 = &s_bf[128 + wid * 64 + g * 4];

    // ---- state: each tile's 16 local elems (ch = 64*wid + 16*(e>>2)+4g+(e&3))
    float yA[16], yB[16];
    {
        const f32x4* x4 = (const f32x4*)x;
        #pragma unroll
        for (int cb = 0; cb < 4; ++cb) {
            f32x4 va = x4[(size_t)rcA * 32 + (wid * 4 + cb) * 4 + g];
            f32x4 vb = x4[(size_t)rcB * 32 + (wid * 4 + cb) * 4 + g];
            #pragma unroll
            for (int r = 0; r < 4; ++r) { yA[cb * 4 + r] = va[r]; yB[cb * 4 + r] = vb[r]; }
        }
    }
    __syncthreads();

    float UA[16], VA[16], UB[16], VB[16];

    #pragma unroll 1
    for (int st = 0; st < 10; ++st) {
        feval2<1>(w1r, w2r, sbf1, sbf2, myA, otA, myB, otB, myHA, otHA, myHB, otHB,
                  yA, UA, VA, yB, UB, VB);
        feval2<2>(w1r, w2r, sbf1, sbf2, myA, otA, myB, otB, myHA, otHA, myHB, otHB,
                  yA, UA, VA, yB, UB, VB);
        feval2<3>(w1r, w2r, sbf1, sbf2, myA, otA, myB, otB, myHA, otHA, myHB, otHB,
                  yA, UA, VA, yB, UB, VB);
        feval2<4>(w1r, w2r, sbf1, sbf2, myA, otA, myB, otB, myHA, otHA, myHB, otHB,
                  yA, UA, VA, yB, UB, VB);
    }

    // ---- epilogue: out^T = Wl^T y^T + bl (wave computes out-ch [32*wid,+32))
    const bf16x8 yA0 = build_frag<1>(yA, UA, VA, 0);
    const bf16x8 yA1 = build_frag<1>(yA, UA, VA, 1);
    const bf16x8 yB0 = build_frag<1>(yB, UB, VB, 0);
    const bf16x8 yB1 = build_frag<1>(yB, UB, VB, 1);
    myA[0]  = __builtin_bit_cast(uint4, yA0);
    myA[64] = __builtin_bit_cast(uint4, yA1);
    myB[0]  = __builtin_bit_cast(uint4, yB0);
    myB[64] = __builtin_bit_cast(uint4, yB1);
    __syncthreads();
    const bf16x8 yA2 = bc8(otA[0]);
    const bf16x8 yA3 = bc8(otA[64]);
    const bf16x8 yB2 = bc8(otB[0]);
    const bf16x8 yB3 = bc8(otB[64]);

    f32x4 aoA[2], aoB[2];
    {
        const f32x4* bl4 = (const f32x4*)bl;
        #pragma unroll
        for (int mb = 0; mb < 2; ++mb) {
            aoA[mb] = bl4[(wid * 2 + mb) * 4 + g];
            aoB[mb] = aoA[mb];
        }
    }
    #pragma unroll
    for (int mb = 0; mb < 2; ++mb) {
        const int fb = 64 + (wid * 2 + mb) * 4;            // Wl frag base (global kb order)
        const int k0 = 2 * wid, k1 = 2 * wid + 1;          // own kbs
        const int k2 = 2 * (1 - wid), k3 = k2 + 1;         // other's kbs
        const bf16x8 wl0 = bc8(wfr[(fb + k0) * 64 + lane]);
        const bf16x8 wl1 = bc8(wfr[(fb + k1) * 64 + lane]);
        const bf16x8 wl2 = bc8(wfr[(fb + k2) * 64 + lane]);
        const bf16x8 wl3 = bc8(wfr[(fb + k3) * 64 + lane]);
        aoA[mb] = MFMA_BF16(wl0, yA0, aoA[mb], 0, 0, 0);
        aoA[mb] = MFMA_BF16(wl1, yA1, aoA[mb], 0, 0, 0);
        aoA[mb] = MFMA_BF16(wl2, yA2, aoA[mb], 0, 0, 0);
        aoA[mb] = MFMA_BF16(wl3, yA3, aoA[mb], 0, 0, 0);
        aoB[mb] = MFMA_BF16(wl0, yB0, aoB[mb], 0, 0, 0);
        aoB[mb] = MFMA_BF16(wl1, yB1, aoB[mb], 0, 0, 0);
        aoB[mb] = MFMA_BF16(wl2, yB2, aoB[mb], 0, 0, 0);
        aoB[mb] = MFMA_BF16(wl3, yB3, aoB[mb], 0, 0, 0);
    }
    f32x4* out4 = (f32x4*)out;
    if (rowA < n) {
        #pragma unroll
        for (int mb = 0; mb < 2; ++mb)
            out4[(size_t)rowA * 16 + (wid * 2 + mb) * 4 + g] = aoA[mb];
    }
    if (rowB < n) {
        #pragma unroll
        for (int mb = 0; mb < 2; ++mb)
            out4[(size_t)rowB * 16 + (wid * 2 + mb) * 4 + g] = aoB[mb];
    }
}

// ---- prep: A-frag-linear bf16 weights into d_ws ----
// A-frag (16x32): lane l, elem j:  row = l&15 (+16*mb),
//                                  k   = 32*kb + 16*(j>>2) + 4*(l>>4) + (j&3)
// wfr[f*64+lane] : f 0..31 = W1 (mb=f>>2,kb=f&3), 32..63 = W2, 64..79 = Wl.
__global__ void prep_kernel(const float* __restrict__ W1, const float* __restrict__ W2,
                            const float* __restrict__ Wl, uint4* __restrict__ wfr)
{
    int t = blockIdx.x * 256 + threadIdx.x;
    if (t >= 80 * 64) return;
    int f = t >> 6, lane = t & 63;
    int gq = lane >> 4, c = lane & 15;
    const float* W; int mb, kv, cols;
    if (f < 32)      { W = W1; mb = f >> 2;        kv = f & 3;        cols = 128; }
    else if (f < 64) { W = W2; mb = (f - 32) >> 2; kv = (f - 32) & 3; cols = 128; }
    else             { W = Wl; mb = (f - 64) >> 2; kv = (f - 64) & 3; cols = 64;  }
    int col = mb * 16 + c;               // output-channel (A row)
    unsigned short v[8];
    #pragma unroll
    for (int j = 0; j < 8; ++j) {
        int k = kv * 32 + (j >> 2) * 16 + gq * 4 + (j & 3);
        v[j] = (unsigned short)__builtin_bit_cast(short, (__bf16)W[k * cols + col]);
    }
    uint4 o;
    o.x = (unsigned)v[0] | ((unsigned)v[1] << 16);
    o.y = (unsigned)v[2] | ((unsigned)v[3] << 16);
    o.z = (unsigned)v[4] | ((unsigned)v[5] << 16);
    o.w = (unsigned)v[6] | ((unsigned)v[7] << 16);
    wfr[t] = o;
}

extern "C" void kernel_launch(void* const* d_in, const int* in_sizes, int n_in,
                              void* d_out, int out_size, void* d_ws, size_t ws_size,
                              hipStream_t stream)
{
    const float* x  = (const float*)d_in[0];
    const float* W1 = (const float*)d_in[1];
    const float* b1 = (const float*)d_in[2];
    const float* W2 = (const float*)d_in[3];
    const float* b2 = (const float*)d_in[4];
    const float* Wl = (const float*)d_in[5];
    const float* bl = (const float*)d_in[6];

    const int n = in_sizes[0] / 128;

    uint4* wfr = (uint4*)d_ws;                       // 80*64*16 = 81920 B

    prep_kernel<<<20, 256, 0, stream>>>(W1, W2, Wl, wfr);

    const int nb = (n + 31) / 32;            // 32 rows per block (2 waves x 2 tiles)
    gnode_kernel<<<nb, 128, 0, stream>>>(x, wfr, b1, b2, bl, (float*)d_out, n);
}

// Round 16
// 487.895 us; speedup vs baseline: 1.3679x; 1.3679x over previous
//
#include <hip/hip_runtime.h>
#include <hip/hip_bf16.h>

// GNODE fully fused: y' = relu(y@W1+b1)@W2+b2, RK4(3/8) x10 steps (h=0.1),
// out = y@Wl+bl.  N=200000 rows, 128 ch, 64 out ch.
//
// Round 16: 4-WAY channel split (from r14's counters: MFMA 620 + VALU 667
// cy/wave-feval are ADDITIVE = 94% of wall; phase-locked waves).  Block =
// 256 thr = 4 waves, 16 rows; wave wid owns out-ch [32wid,+32) of both
// layers.  Natural split: B-frag kb == wave kb's 8 state elems -> each wave
// builds ONE frag/exchange (write 1, read 3).  Per wave-feval: MFMA 310cy,
// VALU ~halved vs r14.  Register target <=128 TOTAL (weights 64 + y 8 +
// U/V packed-bf16 8 + acc 8 + transients) -> 4 waves/SIMD granule.
// Packed-bf16 U/V numerics validated in r10 (passed, absmax 0.0156).
//
// State recurrences (template<MODE>):
//   M1: U<-k1   M2: V<-k2   M3: U<-U+3(V+k3), V<-U-V+k3   M4: y+=h/8(U+k4)
// Layout identity (mfma_f32_16x16x32_bf16, HW-verified m89):
//   D:      ch = 16*MB + 4*(lane>>4) + r,               batch = lane&15
//   B-frag: ch = 32*kb + 16*(j>>2) + 4*(lane>>4)+(j&3),  batch = lane&15
// => frag[kb][j] = state[8*kb + j]; wave wid owns MB {2wid,2wid+1}, i.e.
//    state elems [8wid, 8wid+8) (local j = e - 8wid).  All lane-local.
// Barrier safety: 2 barriers/feval on alternating buffers (argx, hx).

typedef __attribute__((ext_vector_type(8))) short bf16x8;
typedef __attribute__((ext_vector_type(4))) float f32x4;

constexpr float HS = 0.1f;

__device__ __forceinline__ short bf16s(float f) {
    return __builtin_bit_cast(short, (__bf16)f);      // -> v_cvt_pk_bf16_f32 (paired)
}
__device__ __forceinline__ bf16x8 bc8(uint4 u) { return __builtin_bit_cast(bf16x8, u); }
__device__ __forceinline__ float bplo(unsigned u) { return __builtin_bit_cast(float, u << 16); }
__device__ __forceinline__ float bphi(unsigned u) { return __builtin_bit_cast(float, u & 0xffff0000u); }
__device__ __forceinline__ unsigned packbf(float a, float b) {
    unsigned ua = (unsigned short)__builtin_bit_cast(unsigned short, (__bf16)a);
    unsigned ub = (unsigned short)__builtin_bit_cast(unsigned short, (__bf16)b);
    return ua | (ub << 16);
}

#define MFMA_BF16 __builtin_amdgcn_mfma_f32_16x16x32_bf16

// Own B-frag (8 elems) from y (fp32) + packed-bf16 U/V, RK4 combo per mode.
template<int M>
__device__ __forceinline__ bf16x8 build_frag(const float (&y)[8], const unsigned (&Up)[4],
                                             const unsigned (&Vp)[4]) {
    bf16x8 f;
    #pragma unroll
    for (int j = 0; j < 8; ++j) {
        const float Ue = (j & 1) ? bphi(Up[j >> 1]) : bplo(Up[j >> 1]);
        const float Ve = (j & 1) ? bphi(Vp[j >> 1]) : bplo(Vp[j >> 1]);
        float v;
        if (M == 1)      v = y[j];
        else if (M == 2) v = fmaf(HS * (1.f / 3.f), Ue, y[j]);
        else if (M == 3) v = fmaf(-HS * (1.f / 3.f), Ue, fmaf(HS, Ve, y[j]));
        else             v = fmaf(HS, Ve, y[j]);
        f[j] = bf16s(v);
    }
    return f;
}

// One f-eval for this wave's 32-out-ch quarter.  Weight frags wid-relative:
// index f = mb*4 + kl, kl 0 = own kb, kl 1..3 = (wid+kl)&3.
template<int M>
__device__ __forceinline__ void feval(const bf16x8 (&w1r)[8], const bf16x8 (&w2r)[8],
                                      const float* __restrict__ sbf1,
                                      const float* __restrict__ sbf2,
                                      uint4* __restrict__ my_arg,
                                      const uint4* __restrict__ oa1,
                                      const uint4* __restrict__ oa2,
                                      const uint4* __restrict__ oa3,
                                      uint4* __restrict__ my_h,
                                      const uint4* __restrict__ oh1,
                                      const uint4* __restrict__ oh2,
                                      const uint4* __restrict__ oh3,
                                      float (&y)[8], unsigned (&Up)[4], unsigned (&Vp)[4])
{
    // ---- own arg frag -> LDS; bias init overlaps the barrier
    const bf16x8 a0 = build_frag<M>(y, Up, Vp);
    *my_arg = __builtin_bit_cast(uint4, a0);
    f32x4 acc[2];
    acc[0] = *(const f32x4*)&sbf1[0];
    acc[1] = *(const f32x4*)&sbf1[16];
    __syncthreads();
    const bf16x8 a1 = bc8(*oa1);
    const bf16x8 a2 = bc8(*oa2);
    const bf16x8 a3 = bc8(*oa3);

    // ---- matmul1: 8 MFMA (kl0 = own frag from regs)
    __builtin_amdgcn_s_setprio(1);
    acc[0] = MFMA_BF16(w1r[0], a0, acc[0], 0, 0, 0);
    acc[1] = MFMA_BF16(w1r[4], a0, acc[1], 0, 0, 0);
    acc[0] = MFMA_BF16(w1r[1], a1, acc[0], 0, 0, 0);
    acc[1] = MFMA_BF16(w1r[5], a1, acc[1], 0, 0, 0);
    acc[0] = MFMA_BF16(w1r[2], a2, acc[0], 0, 0, 0);
    acc[1] = MFMA_BF16(w1r[6], a2, acc[1], 0, 0, 0);
    acc[0] = MFMA_BF16(w1r[3], a3, acc[0], 0, 0, 0);
    acc[1] = MFMA_BF16(w1r[7], a3, acc[1], 0, 0, 0);
    __builtin_amdgcn_s_setprio(0);

    // ---- relu -> own h frag (h elem j = acc[j>>2][j&3]; adjacent pairs packable)
    bf16x8 hb;
    #pragma unroll
    for (int j = 0; j < 8; ++j)
        hb[j] = bf16s(fmaxf(acc[j >> 2][j & 3], 0.f));
    *my_h = __builtin_bit_cast(uint4, hb);
    f32x4 acc2[2];
    acc2[0] = *(const f32x4*)&sbf2[0];
    acc2[1] = *(const f32x4*)&sbf2[16];
    __syncthreads();
    const bf16x8 h1 = bc8(*oh1);
    const bf16x8 h2 = bc8(*oh2);
    const bf16x8 h3 = bc8(*oh3);

    // ---- matmul2: 8 MFMA
    __builtin_amdgcn_s_setprio(1);
    acc2[0] = MFMA_BF16(w2r[0], hb, acc2[0], 0, 0, 0);
    acc2[1] = MFMA_BF16(w2r[4], hb, acc2[1], 0, 0, 0);
    acc2[0] = MFMA_BF16(w2r[1], h1, acc2[0], 0, 0, 0);
    acc2[1] = MFMA_BF16(w2r[5], h1, acc2[1], 0, 0, 0);
    acc2[0] = MFMA_BF16(w2r[2], h2, acc2[0], 0, 0, 0);
    acc2[1] = MFMA_BF16(w2r[6], h2, acc2[1], 0, 0, 0);
    acc2[0] = MFMA_BF16(w2r[3], h3, acc2[0], 0, 0, 0);
    acc2[1] = MFMA_BF16(w2r[7], h3, acc2[1], 0, 0, 0);
    __builtin_amdgcn_s_setprio(0);

    // ---- mode-fused writeback (pair p covers elems 2p,2p+1; e = 4*mb + r)
    #pragma unroll
    for (int p = 0; p < 4; ++p) {
        const int mb = p >> 1, r0 = (p & 1) * 2;
        const float k0 = acc2[mb][r0], k1 = acc2[mb][r0 + 1];
        if (M == 1)      Up[p] = packbf(k0, k1);
        else if (M == 2) Vp[p] = packbf(k0, k1);
        else if (M == 3) {
            const float u0 = bplo(Up[p]), u1 = bphi(Up[p]);
            const float v0 = bplo(Vp[p]), v1 = bphi(Vp[p]);
            Up[p] = packbf(fmaf(3.f, v0 + k0, u0), fmaf(3.f, v1 + k1, u1));
            Vp[p] = packbf(u0 - v0 + k0, u1 - v1 + k1);
        } else {
            const float u0 = bplo(Up[p]), u1 = bphi(Up[p]);
            y[2 * p]     = fmaf(HS * 0.125f, u0 + k0, y[2 * p]);
            y[2 * p + 1] = fmaf(HS * 0.125f, u1 + k1, y[2 * p + 1]);
        }
    }
}

__global__ __launch_bounds__(256) void gnode_kernel(
    const float* __restrict__ x, const uint4* __restrict__ wfr,
    const float* __restrict__ b1, const float* __restrict__ b2,
    const float* __restrict__ bl, float* __restrict__ out, int n)
{
    __shared__ uint4 argx[4][64];    // 4KB: arg B-frag exchange (slot kb)
    __shared__ uint4 hx[4][64];      // 4KB: hidden B-frag exchange
    __shared__ float s_bf[256];      // 1KB: b1 [0..127], b2 [128..255]

    const int tid  = threadIdx.x;
    const int lane = tid & 63;
    const int wid  = tid >> 6;       // 0..3: which 32-out-ch quarter this wave owns
    const int g    = lane >> 4;
    const int c16  = lane & 15;
    const int row  = blockIdx.x * 16 + c16;   // this lane's batch row
    const int rowc = row < n ? row : n - 1;

    if (wid < 2) s_bf[tid & 127]       = b1[tid & 127];   // waves 0,1 write b1
    else         s_bf[128 + (tid & 127)] = b2[tid & 127]; // waves 2,3 write b2

    // ---- weights: this wave's quarters, wid-RELATIVE kb order kl -> (wid+kl)&3
    bf16x8 w1r[8], w2r[8];
    #pragma unroll
    for (int f = 0; f < 8; ++f) {
        const int mb = f >> 2, kl = f & 3;
        const int kg = (wid + kl) & 3;
        w1r[f] = bc8(wfr[((2 * wid + mb) * 4 + kg) * 64 + lane]);
        w2r[f] = bc8(wfr[(32 + (2 * wid + mb) * 4 + kg) * 64 + lane]);
    }

    // ---- hoisted LDS pointers
    uint4*       my_arg = &argx[wid][lane];
    const uint4* oa1    = &argx[(wid + 1) & 3][lane];
    const uint4* oa2    = &argx[(wid + 2) & 3][lane];
    const uint4* oa3    = &argx[(wid + 3) & 3][lane];
    uint4*       my_h   = &hx[wid][lane];
    const uint4* oh1    = &hx[(wid + 1) & 3][lane];
    const uint4* oh2    = &hx[(wid + 2) & 3][lane];
    const uint4* oh3    = &hx[(wid + 3) & 3][lane];
    const float* sbf1   = &s_bf[32 * wid + 4 * g];
    const float* sbf2   = &s_bf[128 + 32 * wid + 4 * g];

    // ---- state: this wave's 8 elems (ch = 32wid + 16t + 4g + r, t = e>>2)
    float y[8];
    {
        const f32x4* x4 = (const f32x4*)x;
        const f32x4 v0 = x4[(size_t)rowc * 32 + 8 * wid + g];
        const f32x4 v1 = x4[(size_t)rowc * 32 + 8 * wid + 4 + g];
        #pragma unroll
        for (int r = 0; r < 4; ++r) { y[r] = v0[r]; y[4 + r] = v1[r]; }
    }
    __syncthreads();

    unsigned Up[4], Vp[4];

    #pragma unroll 1
    for (int st = 0; st < 10; ++st) {
        feval<1>(w1r, w2r, sbf1, sbf2, my_arg, oa1, oa2, oa3, my_h, oh1, oh2, oh3, y, Up, Vp);
        feval<2>(w1r, w2r, sbf1, sbf2, my_arg, oa1, oa2, oa3, my_h, oh1, oh2, oh3, y, Up, Vp);
        feval<3>(w1r, w2r, sbf1, sbf2, my_arg, oa1, oa2, oa3, my_h, oh1, oh2, oh3, y, Up, Vp);
        feval<4>(w1r, w2r, sbf1, sbf2, my_arg, oa1, oa2, oa3, my_h, oh1, oh2, oh3, y, Up, Vp);
    }

    // ---- epilogue: out^T = Wl^T y^T + bl (wave computes out-ch [16wid,+16))
    bf16x8 yf;
    #pragma unroll
    for (int j = 0; j < 8; ++j) yf[j] = bf16s(y[j]);
    *my_arg = __builtin_bit_cast(uint4, yf);
    __syncthreads();
    const bf16x8 yf1 = bc8(*oa1);
    const bf16x8 yf2 = bc8(*oa2);
    const bf16x8 yf3 = bc8(*oa3);

    f32x4 ao = ((const f32x4*)bl)[wid * 4 + g];          // bl[16wid + 4g + r]
    {
        const int fb = 64 + wid * 4;                     // Wl frag base, global kb order
        ao = MFMA_BF16(bc8(wfr[(fb + ((wid + 0) & 3)) * 64 + lane]), yf,  ao, 0, 0, 0);
        ao = MFMA_BF16(bc8(wfr[(fb + ((wid + 1) & 3)) * 64 + lane]), yf1, ao, 0, 0, 0);
        ao = MFMA_BF16(bc8(wfr[(fb + ((wid + 2) & 3)) * 64 + lane]), yf2, ao, 0, 0, 0);
        ao = MFMA_BF16(bc8(wfr[(fb + ((wid + 3) & 3)) * 64 + lane]), yf3, ao, 0, 0, 0);
    }
    if (row < n)
        ((f32x4*)out)[(size_t)row * 16 + wid * 4 + g] = ao;   // out[row][16wid+4g+r]
}

// ---- prep: A-frag-linear bf16 weights into d_ws ----
// A-frag (16x32): lane l, elem j:  row = l&15 (+16*MB),
//                                  k   = 32*kb + 16*(j>>2) + 4*(l>>4) + (j&3)
// wfr[f*64+lane] : f 0..31 = W1 (MB=f>>2,kb=f&3), 32..63 = W2, 64..79 = Wl.
__global__ void prep_kernel(const float* __restrict__ W1, const float* __restrict__ W2,
                            const float* __restrict__ Wl, uint4* __restrict__ wfr)
{
    int t = blockIdx.x * 256 + threadIdx.x;
    if (t >= 80 * 64) return;
    int f = t >> 6, lane = t & 63;
    int gq = lane >> 4, c = lane & 15;
    const float* W; int mb, kv, cols;
    if (f < 32)      { W = W1; mb = f >> 2;        kv = f & 3;        cols = 128; }
    else if (f < 64) { W = W2; mb = (f - 32) >> 2; kv = (f - 32) & 3; cols = 128; }
    else             { W = Wl; mb = (f - 64) >> 2; kv = (f - 64) & 3; cols = 64;  }
    int col = mb * 16 + c;               // output-channel (A row)
    unsigned short v[8];
    #pragma unroll
    for (int j = 0; j < 8; ++j) {
        int k = kv * 32 + (j >> 2) * 16 + gq * 4 + (j & 3);
        v[j] = (unsigned short)__builtin_bit_cast(short, (__bf16)W[k * cols + col]);
    }
    uint4 o;
    o.x = (unsigned)v[0] | ((unsigned)v[1] << 16);
    o.y = (unsigned)v[2] | ((unsigned)v[3] << 16);
    o.z = (unsigned)v[4] | ((unsigned)v[5] << 16);
    o.w = (unsigned)v[6] | ((unsigned)v[7] << 16);
    wfr[t] = o;
}

extern "C" void kernel_launch(void* const* d_in, const int* in_sizes, int n_in,
                              void* d_out, int out_size, void* d_ws, size_t ws_size,
                              hipStream_t stream)
{
    const float* x  = (const float*)d_in[0];
    const float* W1 = (const float*)d_in[1];
    const float* b1 = (const float*)d_in[2];
    const float* W2 = (const float*)d_in[3];
    const float* b2 = (const float*)d_in[4];
    const float* Wl = (const float*)d_in[5];
    const float* bl = (const float*)d_in[6];

    const int n = in_sizes[0] / 128;

    uint4* wfr = (uint4*)d_ws;                       // 80*64*16 = 81920 B

    prep_kernel<<<20, 256, 0, stream>>>(W1, W2, Wl, wfr);

    const int nb = (n + 15) / 16;            // 16 rows per block (4 waves)
    gnode_kernel<<<nb, 256, 0, stream>>>(x, wfr, b1, b2, bl, (float*)d_out, n);
}

// Round 17
// 465.885 us; speedup vs baseline: 1.4325x; 1.0472x over previous
//
#include <hip/hip_runtime.h>
#include <hip/hip_bf16.h>

// GNODE fully fused: y' = relu(y@W1+b1)@W2+b2, RK4(3/8) x10 steps (h=0.1),
// out = y@Wl+bl.  N=200000 rows, 128 ch, 64 out ch.
//
// Round 17 = r16 (4-way channel split, 3 waves/SIMD, VGPR 68+~80AGPR) with
// U/V state UNPACKED to fp32.  r16 counters: VALUBusy 59 > MfmaUtil 43,
// ~200 VALU instr/feval vs ~60 essential; the packed-bf16 U/V cost ~50
// instr/feval of bplo/bphi/packbf while buying registers we don't need
// (68 arch).  Now: build_frag = fma+cvt only; M1/M2 writeback = copies;
// M3/M4 = fp32 fma.  Budget ~84 arch + 80 AGPR = ~164 -> stays in the
// 3-waves/SIMD window (<=170 total).  Numerics strictly better than r16.
//
// Structure: block = 256 thr = 4 waves, 16 rows; wave wid owns out-ch
// [32wid,+32) of both layers; weights 16 A-frags = 64 regs (AGPR-resident).
// B-frag kb == wave kb's 8 state elems -> exchange = write 1, read 3.
//
// State recurrences (template<MODE>):
//   M1: U<-k1   M2: V<-k2   M3: U<-U+3(V+k3), V<-U-V+k3   M4: y+=h/8(U+k4)
// Layout identity (mfma_f32_16x16x32_bf16, HW-verified m89):
//   D:      ch = 16*MB + 4*(lane>>4) + r,               batch = lane&15
//   B-frag: ch = 32*kb + 16*(j>>2) + 4*(lane>>4)+(j&3),  batch = lane&15
// => frag[kb][j] = state[8*kb + j]; wave wid owns MB {2wid,2wid+1}, i.e.
//    state elems [8wid, 8wid+8).  All lane-local.
// Barrier safety: 2 barriers/feval on alternating buffers (argx, hx).

typedef __attribute__((ext_vector_type(8))) short bf16x8;
typedef __attribute__((ext_vector_type(4))) float f32x4;

constexpr float HS = 0.1f;

__device__ __forceinline__ short bf16s(float f) {
    return __builtin_bit_cast(short, (__bf16)f);      // -> v_cvt_pk_bf16_f32 (paired)
}
__device__ __forceinline__ bf16x8 bc8(uint4 u) { return __builtin_bit_cast(bf16x8, u); }

#define MFMA_BF16 __builtin_amdgcn_mfma_f32_16x16x32_bf16

// Own B-frag (8 elems) from fp32 y/U/V, RK4 combo fused per mode.
template<int M>
__device__ __forceinline__ bf16x8 build_frag(const float (&y)[8], const float (&U)[8],
                                             const float (&V)[8]) {
    bf16x8 f;
    #pragma unroll
    for (int j = 0; j < 8; ++j) {
        float v;
        if (M == 1)      v = y[j];
        else if (M == 2) v = fmaf(HS * (1.f / 3.f), U[j], y[j]);
        else if (M == 3) v = fmaf(-HS * (1.f / 3.f), U[j], fmaf(HS, V[j], y[j]));
        else             v = fmaf(HS, V[j], y[j]);
        f[j] = bf16s(v);
    }
    return f;
}

// One f-eval for this wave's 32-out-ch quarter.  Weight frags wid-relative:
// index f = mb*4 + kl, kl 0 = own kb, kl 1..3 = (wid+kl)&3.
template<int M>
__device__ __forceinline__ void feval(const bf16x8 (&w1r)[8], const bf16x8 (&w2r)[8],
                                      const float* __restrict__ sbf1,
                                      const float* __restrict__ sbf2,
                                      uint4* __restrict__ my_arg,
                                      const uint4* __restrict__ oa1,
                                      const uint4* __restrict__ oa2,
                                      const uint4* __restrict__ oa3,
                                      uint4* __restrict__ my_h,
                                      const uint4* __restrict__ oh1,
                                      const uint4* __restrict__ oh2,
                                      const uint4* __restrict__ oh3,
                                      float (&y)[8], float (&U)[8], float (&V)[8])
{
    // ---- own arg frag -> LDS; bias init overlaps the barrier
    const bf16x8 a0 = build_frag<M>(y, U, V);
    *my_arg = __builtin_bit_cast(uint4, a0);
    f32x4 acc[2];
    acc[0] = *(const f32x4*)&sbf1[0];
    acc[1] = *(const f32x4*)&sbf1[16];
    __syncthreads();
    const bf16x8 a1 = bc8(*oa1);
    const bf16x8 a2 = bc8(*oa2);
    const bf16x8 a3 = bc8(*oa3);

    // ---- matmul1: 8 MFMA (kl0 = own frag from regs)
    __builtin_amdgcn_s_setprio(1);
    acc[0] = MFMA_BF16(w1r[0], a0, acc[0], 0, 0, 0);
    acc[1] = MFMA_BF16(w1r[4], a0, acc[1], 0, 0, 0);
    acc[0] = MFMA_BF16(w1r[1], a1, acc[0], 0, 0, 0);
    acc[1] = MFMA_BF16(w1r[5], a1, acc[1], 0, 0, 0);
    acc[0] = MFMA_BF16(w1r[2], a2, acc[0], 0, 0, 0);
    acc[1] = MFMA_BF16(w1r[6], a2, acc[1], 0, 0, 0);
    acc[0] = MFMA_BF16(w1r[3], a3, acc[0], 0, 0, 0);
    acc[1] = MFMA_BF16(w1r[7], a3, acc[1], 0, 0, 0);
    __builtin_amdgcn_s_setprio(0);

    // ---- relu -> own h frag (h elem j = acc[j>>2][j&3]; adjacent pairs packable)
    bf16x8 hb;
    #pragma unroll
    for (int j = 0; j < 8; ++j)
        hb[j] = bf16s(fmaxf(acc[j >> 2][j & 3], 0.f));
    *my_h = __builtin_bit_cast(uint4, hb);
    f32x4 acc2[2];
    acc2[0] = *(const f32x4*)&sbf2[0];
    acc2[1] = *(const f32x4*)&sbf2[16];
    __syncthreads();
    const bf16x8 h1 = bc8(*oh1);
    const bf16x8 h2 = bc8(*oh2);
    const bf16x8 h3 = bc8(*oh3);

    // ---- matmul2: 8 MFMA
    __builtin_amdgcn_s_setprio(1);
    acc2[0] = MFMA_BF16(w2r[0], hb, acc2[0], 0, 0, 0);
    acc2[1] = MFMA_BF16(w2r[4], hb, acc2[1], 0, 0, 0);
    acc2[0] = MFMA_BF16(w2r[1], h1, acc2[0], 0, 0, 0);
    acc2[1] = MFMA_BF16(w2r[5], h1, acc2[1], 0, 0, 0);
    acc2[0] = MFMA_BF16(w2r[2], h2, acc2[0], 0, 0, 0);
    acc2[1] = MFMA_BF16(w2r[6], h2, acc2[1], 0, 0, 0);
    acc2[0] = MFMA_BF16(w2r[3], h3, acc2[0], 0, 0, 0);
    acc2[1] = MFMA_BF16(w2r[7], h3, acc2[1], 0, 0, 0);
    __builtin_amdgcn_s_setprio(0);

    // ---- mode-fused writeback (e = 4*mb + r, all fp32)
    #pragma unroll
    for (int e = 0; e < 8; ++e) {
        const float k = acc2[e >> 2][e & 3];
        if (M == 1)      U[e] = k;
        else if (M == 2) V[e] = k;
        else if (M == 3) {
            const float u = U[e], v = V[e];
            U[e] = fmaf(3.f, v + k, u);
            V[e] = u - v + k;
        } else {
            y[e] = fmaf(HS * 0.125f, U[e] + k, y[e]);
        }
    }
}

__global__ __launch_bounds__(256) void gnode_kernel(
    const float* __restrict__ x, const uint4* __restrict__ wfr,
    const float* __restrict__ b1, const float* __restrict__ b2,
    const float* __restrict__ bl, float* __restrict__ out, int n)
{
    __shared__ uint4 argx[4][64];    // 4KB: arg B-frag exchange (slot kb)
    __shared__ uint4 hx[4][64];      // 4KB: hidden B-frag exchange
    __shared__ float s_bf[256];      // 1KB: b1 [0..127], b2 [128..255]

    const int tid  = threadIdx.x;
    const int lane = tid & 63;
    const int wid  = tid >> 6;       // 0..3: which 32-out-ch quarter this wave owns
    const int g    = lane >> 4;
    const int c16  = lane & 15;
    const int row  = blockIdx.x * 16 + c16;   // this lane's batch row
    const int rowc = row < n ? row : n - 1;

    if (wid < 2) s_bf[tid & 127]         = b1[tid & 127];   // waves 0,1 write b1
    else         s_bf[128 + (tid & 127)] = b2[tid & 127];   // waves 2,3 write b2

    // ---- weights: this wave's quarters, wid-RELATIVE kb order kl -> (wid+kl)&3
    bf16x8 w1r[8], w2r[8];
    #pragma unroll
    for (int f = 0; f < 8; ++f) {
        const int mb = f >> 2, kl = f & 3;
        const int kg = (wid + kl) & 3;
        w1r[f] = bc8(wfr[((2 * wid + mb) * 4 + kg) * 64 + lane]);
        w2r[f] = bc8(wfr[(32 + (2 * wid + mb) * 4 + kg) * 64 + lane]);
    }

    // ---- hoisted LDS pointers
    uint4*       my_arg = &argx[wid][lane];
    const uint4* oa1    = &argx[(wid + 1) & 3][lane];
    const uint4* oa2    = &argx[(wid + 2) & 3][lane];
    const uint4* oa3    = &argx[(wid + 3) & 3][lane];
    uint4*       my_h   = &hx[wid][lane];
    const uint4* oh1    = &hx[(wid + 1) & 3][lane];
    const uint4* oh2    = &hx[(wid + 2) & 3][lane];
    const uint4* oh3    = &hx[(wid + 3) & 3][lane];
    const float* sbf1   = &s_bf[32 * wid + 4 * g];
    const float* sbf2   = &s_bf[128 + 32 * wid + 4 * g];

    // ---- state: this wave's 8 elems (ch = 32wid + 16t + 4g + r, t = e>>2)
    float y[8];
    {
        const f32x4* x4 = (const f32x4*)x;
        const f32x4 v0 = x4[(size_t)rowc * 32 + 8 * wid + g];
        const f32x4 v1 = x4[(size_t)rowc * 32 + 8 * wid + 4 + g];
        #pragma unroll
        for (int r = 0; r < 4; ++r) { y[r] = v0[r]; y[4 + r] = v1[r]; }
    }
    __syncthreads();

    float U[8], V[8];

    #pragma unroll 1
    for (int st = 0; st < 10; ++st) {
        feval<1>(w1r, w2r, sbf1, sbf2, my_arg, oa1, oa2, oa3, my_h, oh1, oh2, oh3, y, U, V);
        feval<2>(w1r, w2r, sbf1, sbf2, my_arg, oa1, oa2, oa3, my_h, oh1, oh2, oh3, y, U, V);
        feval<3>(w1r, w2r, sbf1, sbf2, my_arg, oa1, oa2, oa3, my_h, oh1, oh2, oh3, y, U, V);
        feval<4>(w1r, w2r, sbf1, sbf2, my_arg, oa1, oa2, oa3, my_h, oh1, oh2, oh3, y, U, V);
    }

    // ---- epilogue: out^T = Wl^T y^T + bl (wave computes out-ch [16wid,+16))
    bf16x8 yf;
    #pragma unroll
    for (int j = 0; j < 8; ++j) yf[j] = bf16s(y[j]);
    *my_arg = __builtin_bit_cast(uint4, yf);
    __syncthreads();
    const bf16x8 yf1 = bc8(*oa1);
    const bf16x8 yf2 = bc8(*oa2);
    const bf16x8 yf3 = bc8(*oa3);

    f32x4 ao = ((const f32x4*)bl)[wid * 4 + g];          // bl[16wid + 4g + r]
    {
        const int fb = 64 + wid * 4;                     // Wl frag base, global kb order
        ao = MFMA_BF16(bc8(wfr[(fb + ((wid + 0) & 3)) * 64 + lane]), yf,  ao, 0, 0, 0);
        ao = MFMA_BF16(bc8(wfr[(fb + ((wid + 1) & 3)) * 64 + lane]), yf1, ao, 0, 0, 0);
        ao = MFMA_BF16(bc8(wfr[(fb + ((wid + 2) & 3)) * 64 + lane]), yf2, ao, 0, 0, 0);
        ao = MFMA_BF16(bc8(wfr[(fb + ((wid + 3) & 3)) * 64 + lane]), yf3, ao, 0, 0, 0);
    }
    if (row < n)
        ((f32x4*)out)[(size_t)row * 16 + wid * 4 + g] = ao;   // out[row][16wid+4g+r]
}

// ---- prep: A-frag-linear bf16 weights into d_ws ----
// A-frag (16x32): lane l, elem j:  row = l&15 (+16*MB),
//                                  k   = 32*kb + 16*(j>>2) + 4*(l>>4) + (j&3)
// wfr[f*64+lane] : f 0..31 = W1 (MB=f>>2,kb=f&3), 32..63 = W2, 64..79 = Wl.
__global__ void prep_kernel(const float* __restrict__ W1, const float* __restrict__ W2,
                            const float* __restrict__ Wl, uint4* __restrict__ wfr)
{
    int t = blockIdx.x * 256 + threadIdx.x;
    if (t >= 80 * 64) return;
    int f = t >> 6, lane = t & 63;
    int gq = lane >> 4, c = lane & 15;
    const float* W; int mb, kv, cols;
    if (f < 32)      { W = W1; mb = f >> 2;        kv = f & 3;        cols = 128; }
    else if (f < 64) { W = W2; mb = (f - 32) >> 2; kv = (f - 32) & 3; cols = 128; }
    else             { W = Wl; mb = (f - 64) >> 2; kv = (f - 64) & 3; cols = 64;  }
    int col = mb * 16 + c;               // output-channel (A row)
    unsigned short v[8];
    #pragma unroll
    for (int j = 0; j < 8; ++j) {
        int k = kv * 32 + (j >> 2) * 16 + gq * 4 + (j & 3);
        v[j] = (unsigned short)__builtin_bit_cast(short, (__bf16)W[k * cols + col]);
    }
    uint4 o;
    o.x = (unsigned)v[0] | ((unsigned)v[1] << 16);
    o.y = (unsigned)v[2] | ((unsigned)v[3] << 16);
    o.z = (unsigned)v[4] | ((unsigned)v[5] << 16);
    o.w = (unsigned)v[6] | ((unsigned)v[7] << 16);
    wfr[t] = o;
}

extern "C" void kernel_launch(void* const* d_in, const int* in_sizes, int n_in,
                              void* d_out, int out_size, void* d_ws, size_t ws_size,
                              hipStream_t stream)
{
    const float* x  = (const float*)d_in[0];
    const float* W1 = (const float*)d_in[1];
    const float* b1 = (const float*)d_in[2];
    const float* W2 = (const float*)d_in[3];
    const float* b2 = (const float*)d_in[4];
    const float* Wl = (const float*)d_in[5];
    const float* bl = (const float*)d_in[6];

    const int n = in_sizes[0] / 128;

    uint4* wfr = (uint4*)d_ws;                       // 80*64*16 = 81920 B

    prep_kernel<<<20, 256, 0, stream>>>(W1, W2, Wl, wfr);

    const int nb = (n + 15) / 16;            // 16 rows per block (4 waves)
    gnode_kernel<<<nb, 256, 0, stream>>>(x, wfr, b1, b2, bl, (float*)d_out, n);
}